// Round 10
// baseline (1431.309 us; speedup 1.0000x reference)
//
#include <hip/hip_runtime.h>

#define NCH 64
#define NBLK 512          // blocks for coarse hist/scatter
#define CB 1024           // coarse bins (dst >> 7): 128-node buckets

typedef unsigned int uint;
typedef short short8 __attribute__((ext_vector_type(8)));
typedef float floatx4 __attribute__((ext_vector_type(4)));

// bf16 helpers: pack with round-to-nearest-even, unpack via bit shifts
__device__ inline uint bf16rne(float f) {
    uint u = __float_as_uint(f);
    return (u + 0x7fffu + ((u >> 16) & 1u)) >> 16;
}
__device__ inline uint pack2bf(float lo, float hi) {
    return bf16rne(lo) | (bf16rne(hi) << 16);
}
__device__ inline float unpLo(uint v) { return __uint_as_float(v << 16); }
__device__ inline float unpHi(uint v) { return __uint_as_float(v & 0xffff0000u); }

// ---------------- bucket build: one-level counting bucket (128-node buckets) ----------------

__global__ void coarse_hist_kernel(const int* __restrict__ dst, int* __restrict__ cntCB,
                                   int ne, int epb) {
    __shared__ int h[CB];
    int t = threadIdx.x;
    for (int i = t; i < CB; i += blockDim.x) h[i] = 0;
    __syncthreads();
    int e0 = blockIdx.x * epb;
    int e1 = min(e0 + epb, ne);
    for (int e = e0 + t; e < e1; e += blockDim.x)
        atomicAdd(&h[dst[e] >> 7], 1);
    __syncthreads();
    for (int i = t; i < CB; i += blockDim.x) cntCB[i * NBLK + blockIdx.x] = h[i];
}

// one block per bin: exclusive scan of its NBLK counts; binTot[bin] = total
__global__ void binscan_kernel(int* __restrict__ cntCB, int* __restrict__ binTot) {
    __shared__ int s[NBLK];
    int bin = blockIdx.x;
    int t = threadIdx.x;              // NBLK threads
    int v = cntCB[bin * NBLK + t];
    s[t] = v;
    __syncthreads();
    for (int off = 1; off < NBLK; off <<= 1) {
        int add = (t >= off) ? s[t - off] : 0;
        __syncthreads();
        s[t] += add;
        __syncthreads();
    }
    cntCB[bin * NBLK + t] = s[t] - v;               // exclusive within bin
    if (t == NBLK - 1) binTot[bin] = s[t];
}

// single block: exclusive scan of CB bin totals -> cb[]
__global__ void cbscan_kernel(const int* __restrict__ binTot, int* __restrict__ cb, int ne) {
    __shared__ int s[CB];
    int t = threadIdx.x;              // CB threads
    int v = binTot[t];
    s[t] = v;
    __syncthreads();
    for (int off = 1; off < CB; off <<= 1) {
        int add = (t >= off) ? s[t - off] : 0;
        __syncthreads();
        s[t] += add;
        __syncthreads();
    }
    cb[t] = s[t] - v;                               // exclusive
    if (t == CB - 1) cb[CB] = ne;
}

// scatter packed (dstLocal<<24 | src) into buckets; per-(bin,block) regions private
__global__ void coarse_scatter_kernel(const int* __restrict__ src, const int* __restrict__ dst,
                                      const int* __restrict__ cntCB, const int* __restrict__ cb,
                                      uint* __restrict__ packed, int ne, int epb) {
    __shared__ int cur[CB];
    int t = threadIdx.x;
    for (int i = t; i < CB; i += blockDim.x)
        cur[i] = cb[i] + cntCB[i * NBLK + blockIdx.x];
    __syncthreads();
    int e0 = blockIdx.x * epb;
    int e1 = min(e0 + epb, ne);
    for (int e = e0 + t; e < e1; e += blockDim.x) {
        int d = dst[e];
        int pos = atomicAdd(&cur[d >> 7], 1);       // LDS atomic
        packed[pos] = ((uint)(d & 127) << 24) | (uint)src[e];
    }
}

// per-bucket degree hist -> dinv (needed before gemm1)
__global__ void dinvhist_kernel(const uint* __restrict__ packed, const int* __restrict__ cb,
                                float* __restrict__ dinv, int n) {
    __shared__ int h[128];
    int k = blockIdx.x, t = threadIdx.x;            // 128 threads
    h[t] = 0;
    __syncthreads();
    int e0 = cb[k], e1 = cb[k + 1];
    for (int e = e0 + t; e < e1; e += 128)
        atomicAdd(&h[packed[e] >> 24], 1);
    __syncthreads();
    int node = (k << 7) + t;
    if (node < n) dinv[node] = rsqrtf(1.f + (float)h[t]);
}

// ---------------- W -> bf16 MFMA B-fragments (once per call) ----------------
__global__ void wfrag_kernel(const float* __restrict__ W1, const float* __restrict__ W2,
                             uint4* __restrict__ frag) {
    int tid = blockIdx.x * blockDim.x + threadIdx.x;   // 0..1023
    if (tid >= 1024) return;
    int mat = tid >> 9;
    int rem = tid & 511;
    int nt = rem >> 7;
    int kb = (rem >> 6) & 1;
    int lane = rem & 63;
    const float* W = mat ? W2 : W1;
    int kbase = kb * 32 + (lane >> 4) * 8;
    int col = nt * 16 + (lane & 15);
    uint r[4];
#pragma unroll
    for (int j = 0; j < 4; ++j) {
        float lo = W[(kbase + 2 * j) * NCH + col];
        float hi = W[(kbase + 2 * j + 1) * NCH + col];
        r[j] = pack2bf(lo, hi);                       // slot 2j low, 2j+1 high (ascending k)
    }
    frag[tid] = make_uint4(r[0], r[1], r[2], r[3]);
}

// ---------------- H(bf16) = dinv[row] * X @ W via MFMA ----------------
// BF16A=false: X is f32 rows. BF16A=true: X is bf16 rows in (w,w+32)-packed words.
// Output word w of row = channels (w, w+32):  H[row][w] = pack(h[w], h[w+32]).
template<bool BF16A>
__global__ void gemm_mfma_kernel(const void* __restrict__ Xv, const uint4* __restrict__ wfrag,
                                 const float* __restrict__ dinv, uint* __restrict__ H, int n) {
    int lane = threadIdx.x & 63;
    int wave = blockIdx.x * (blockDim.x >> 6) + (threadIdx.x >> 6);
    int rb = wave * 16;
    if (rb >= n) return;

    short8 bfrag[4][2];
#pragma unroll
    for (int nt = 0; nt < 4; ++nt)
#pragma unroll
        for (int kb = 0; kb < 2; ++kb) {
            uint4 u = wfrag[(nt * 2 + kb) * 64 + lane];
            bfrag[nt][kb] = *(short8*)&u;
        }

    short8 afrag[2];
    if (BF16A) {
        const uint* hr = (const uint*)Xv + (long long)(rb + (lane & 15)) * 32 + (lane >> 4) * 8;
        uint4 a0 = *(const uint4*)(hr);
        uint4 a1 = *(const uint4*)(hr + 4);
        uint w[8] = {a0.x, a0.y, a0.z, a0.w, a1.x, a1.y, a1.z, a1.w};
        short8 f0, f1;
#pragma unroll
        for (int j = 0; j < 8; ++j) {
            f0[j] = (short)(w[j] & 0xffffu);
            f1[j] = (short)(w[j] >> 16);
        }
        afrag[0] = f0;
        afrag[1] = f1;
    } else {
        const float* xr = (const float*)Xv + (long long)(rb + (lane & 15)) * NCH + (lane >> 4) * 8;
#pragma unroll
        for (int kb = 0; kb < 2; ++kb) {
            float4 v0 = *(const float4*)(xr + kb * 32);
            float4 v1 = *(const float4*)(xr + kb * 32 + 4);
            short8 a;
            a[0] = (short)bf16rne(v0.x); a[1] = (short)bf16rne(v0.y);
            a[2] = (short)bf16rne(v0.z); a[3] = (short)bf16rne(v0.w);
            a[4] = (short)bf16rne(v1.x); a[5] = (short)bf16rne(v1.y);
            a[6] = (short)bf16rne(v1.z); a[7] = (short)bf16rne(v1.w);
            afrag[kb] = a;
        }
    }

    floatx4 acc[4];
#pragma unroll
    for (int nt = 0; nt < 4; ++nt) acc[nt] = (floatx4){0.f, 0.f, 0.f, 0.f};
#pragma unroll
    for (int nt = 0; nt < 4; ++nt)
#pragma unroll
        for (int kb = 0; kb < 2; ++kb)
            acc[nt] = __builtin_amdgcn_mfma_f32_16x16x32_bf16(afrag[kb], bfrag[nt][kb], acc[nt], 0, 0, 0);

    int r0 = rb + (lane >> 4) * 4;
#pragma unroll
    for (int reg = 0; reg < 4; ++reg) {
        float di = dinv[r0 + reg];
        long long roww = (long long)(r0 + reg) * 32;
#pragma unroll
        for (int nt = 0; nt < 2; ++nt) {
            int w = nt * 16 + (lane & 15);
            H[roww + w] = pack2bf(di * acc[nt][reg], di * acc[nt + 2][reg]);
        }
    }
}

// ---------------- bucketagg: block per 128-node bucket, LDS f32 accumulation ----------------
// acc row stride 68 floats (272 B) skews banks so concurrent ds_adds to different
// dst rows rarely collide. Init = self-loop row; stream edges 8-deep; epilogue
// applies dinv*(.)+bias (+relu/bf16 pack for layer-1 output).
#define RSTRIDE 68
template<bool BF16OUT>
__launch_bounds__(256, 4)
__global__ void bucketagg_kernel(const uint* __restrict__ hsB, const uint* __restrict__ packed,
                                 const int* __restrict__ cb, const float* __restrict__ dinv,
                                 const float* __restrict__ bias, void* __restrict__ outv, int n) {
    __shared__ float acc[128 * RSTRIDE];              // 34816 B
    int k = blockIdx.x;
    int t = threadIdx.x;
    int u = t & 15;                                   // uint2 slot: words 2u,2u+1
    int nb = k << 7;
    // ---- init with self-loop rows ----
#pragma unroll
    for (int p = 0; p < 8; ++p) {
        int li = p * 16 + (t >> 4);
        int node = nb + li;
        if (node < n) {
            uint2 v = *((const uint2*)hsB + (long long)node * 16 + u);
            float* r = acc + li * RSTRIDE;
            r[2 * u]      = unpLo(v.x);
            r[2 * u + 1]  = unpLo(v.y);
            r[2 * u + 32] = unpHi(v.x);
            r[2 * u + 33] = unpHi(v.y);
        }
    }
    __syncthreads();
    // ---- stream edges: wave w takes 32-edge chunks, quarter q owns edge 4r+q ----
    int e0 = cb[k], e1 = cb[k + 1];
    int w = t >> 6;
    int q = (t >> 4) & 3;
    for (int eb = e0 + w * 32; eb < e1; eb += 128) {
        uint pw[8];
#pragma unroll
        for (int r = 0; r < 8; ++r) {
            int idx = eb + 4 * r + q;
            pw[r] = (idx < e1) ? packed[idx] : 0xFFFFFFFFu;   // sentinel (valid < 2^31)
        }
        uint2 v[8];
#pragma unroll
        for (int r = 0; r < 8; ++r) {
            int src = (pw[r] == 0xFFFFFFFFu) ? 0 : (int)(pw[r] & 0x00FFFFFFu);
            v[r] = *((const uint2*)hsB + (long long)src * 16 + u);
        }
#pragma unroll
        for (int r = 0; r < 8; ++r) {
            if (pw[r] != 0xFFFFFFFFu) {
                float* rr = acc + (int)(pw[r] >> 24) * RSTRIDE;
                atomicAdd(rr + 2 * u,      unpLo(v[r].x));
                atomicAdd(rr + 2 * u + 1,  unpLo(v[r].y));
                atomicAdd(rr + 2 * u + 32, unpHi(v[r].x));
                atomicAdd(rr + 2 * u + 33, unpHi(v[r].y));
            }
        }
    }
    __syncthreads();
    // ---- epilogue ----
#pragma unroll
    for (int p = 0; p < 8; ++p) {
        int li = p * 16 + (t >> 4);
        int node = nb + li;
        if (node < n) {
            float d = dinv[node];
            const float* r = acc + li * RSTRIDE;
            float r00 = d * r[2 * u]      + bias[2 * u];
            float r01 = d * r[2 * u + 1]  + bias[2 * u + 1];
            float r10 = d * r[2 * u + 32] + bias[2 * u + 32];
            float r11 = d * r[2 * u + 33] + bias[2 * u + 33];
            if (BF16OUT) {
                uint w0 = pack2bf(fmaxf(r00, 0.f), fmaxf(r10, 0.f));
                uint w1 = pack2bf(fmaxf(r01, 0.f), fmaxf(r11, 0.f));
                *((uint2*)outv + (long long)node * 16 + u) = make_uint2(w0, w1);
            } else {
                float* out = (float*)outv;
                *(float2*)(out + (long long)node * NCH + 2 * u) = make_float2(r00, r01);
                *(float2*)(out + (long long)node * NCH + 2 * u + 32) = make_float2(r10, r11);
            }
        }
    }
}

extern "C" void kernel_launch(void* const* d_in, const int* in_sizes, int n_in,
                              void* d_out, int out_size, void* d_ws, size_t ws_size,
                              hipStream_t stream) {
    const float* x  = (const float*)d_in[0];
    const int*   ei = (const int*)d_in[1];
    const float* W1 = (const float*)d_in[2];
    const float* b1 = (const float*)d_in[3];
    const float* W2 = (const float*)d_in[4];
    const float* b2 = (const float*)d_in[5];
    const int n  = in_sizes[0] / NCH;   // 100000
    const int ne = in_sizes[1] / 2;     // 1600000
    const int* src = ei;
    const int* dst = ei + ne;

    // workspace layout (all 256B-aligned)
    char* ws = (char*)d_ws;
    size_t off = 0;
    auto alloc = [&](size_t bytes) { void* p = ws + off; off += (bytes + 255) & ~(size_t)255; return p; };
    int*   cntCB   = (int*)alloc((size_t)CB * NBLK * 4);       // 2 MB
    int*   binTot  = (int*)alloc((size_t)CB * 4);
    int*   cb      = (int*)alloc((size_t)(CB + 1) * 4);
    float* dinv    = (float*)alloc((size_t)n * 4);
    uint*  packed  = (uint*)alloc((size_t)ne * 4 + 128);       // 6.4 MB
    uint*  hsB     = (uint*)alloc((size_t)n * 32 * 4);         // 12.8 MB (gemm out, bf16)
    uint*  hsB2    = (uint*)alloc((size_t)n * 32 * 4);         // 12.8 MB (agg1 out, relu bf16)
    uint4* wfrag   = (uint4*)alloc(1024 * 16);                 // 16 KB

    const int blk = 256;
    const int epb  = (ne + NBLK - 1) / NBLK;
    const int nBuck = (n + 127) >> 7;                          // 782 buckets
    const int nWaveG = (n + 15) / 16;
    const int gGemm = (nWaveG + 3) / 4;

    // ---- bucket build (no global atomics) + W fragment pack ----
    wfrag_kernel         <<<4, 256, 0, stream>>>(W1, W2, wfrag);
    coarse_hist_kernel   <<<NBLK, blk, 0, stream>>>(dst, cntCB, ne, epb);
    binscan_kernel       <<<CB, NBLK, 0, stream>>>(cntCB, binTot);
    cbscan_kernel        <<<1, CB, 0, stream>>>(binTot, cb, ne);
    coarse_scatter_kernel<<<NBLK, blk, 0, stream>>>(src, dst, cntCB, cb, packed, ne, epb);
    dinvhist_kernel      <<<nBuck, 128, 0, stream>>>(packed, cb, dinv, n);

    // ---- layer 1 ----
    gemm_mfma_kernel<false><<<gGemm, blk, 0, stream>>>(x, wfrag, dinv, hsB, n);
    bucketagg_kernel<true><<<nBuck, blk, 0, stream>>>(hsB, packed, cb, dinv, b1, hsB2, n);

    // ---- layer 2 (relu pre-applied by agg1; A read as packed bf16) ----
    gemm_mfma_kernel<true><<<gGemm, blk, 0, stream>>>(hsB2, wfrag + 512, dinv, hsB, n);
    bucketagg_kernel<false><<<nBuck, blk, 0, stream>>>(hsB, packed, cb, dinv, b2, d_out, n);
}

// Round 11
// 145.539 us; speedup vs baseline: 9.8346x; 9.8346x over previous
//
#include <hip/hip_runtime.h>

#define NCH 64
#define NBLK 512          // blocks for coarse hist/scatter
#define CB 512            // coarse bins (dst >> 8): 256-node buckets

typedef unsigned int uint;
typedef short short8 __attribute__((ext_vector_type(8)));
typedef float floatx4 __attribute__((ext_vector_type(4)));

// bf16 helpers: pack with round-to-nearest-even, unpack via bit shifts
__device__ inline uint bf16rne(float f) {
    uint u = __float_as_uint(f);
    return (u + 0x7fffu + ((u >> 16) & 1u)) >> 16;
}
__device__ inline uint pack2bf(float lo, float hi) {
    return bf16rne(lo) | (bf16rne(hi) << 16);
}
__device__ inline float unpLo(uint v) { return __uint_as_float(v << 16); }
__device__ inline float unpHi(uint v) { return __uint_as_float(v & 0xffff0000u); }

// ---------------- CSR build: two-level counting sort, LDS atomics only ----------------

__global__ void coarse_hist_kernel(const int* __restrict__ dst, int* __restrict__ cntCB,
                                   int ne, int epb) {
    __shared__ int h[CB];
    int t = threadIdx.x;
    for (int i = t; i < CB; i += blockDim.x) h[i] = 0;
    __syncthreads();
    int e0 = blockIdx.x * epb;
    int e1 = min(e0 + epb, ne);
    for (int e = e0 + t; e < e1; e += blockDim.x)
        atomicAdd(&h[dst[e] >> 8], 1);
    __syncthreads();
    for (int i = t; i < CB; i += blockDim.x) cntCB[i * NBLK + blockIdx.x] = h[i];
}

__global__ void binscan_kernel(int* __restrict__ cntCB, int* __restrict__ binTot) {
    __shared__ int s[NBLK];
    int bin = blockIdx.x;
    int t = threadIdx.x;              // NBLK threads
    int v = cntCB[bin * NBLK + t];
    s[t] = v;
    __syncthreads();
    for (int off = 1; off < NBLK; off <<= 1) {
        int add = (t >= off) ? s[t - off] : 0;
        __syncthreads();
        s[t] += add;
        __syncthreads();
    }
    cntCB[bin * NBLK + t] = s[t] - v;               // exclusive within bin
    if (t == NBLK - 1) binTot[bin] = s[t];
}

__global__ void cbscan_kernel(const int* __restrict__ binTot, int* __restrict__ cb,
                              int* __restrict__ rowptr, int n, int ne) {
    __shared__ int s[CB];
    int t = threadIdx.x;              // CB threads
    int v = binTot[t];
    s[t] = v;
    __syncthreads();
    for (int off = 1; off < CB; off <<= 1) {
        int add = (t >= off) ? s[t - off] : 0;
        __syncthreads();
        s[t] += add;
        __syncthreads();
    }
    cb[t] = s[t] - v;                               // exclusive
    if (t == CB - 1) { cb[CB] = ne; rowptr[n] = ne; }
}

// scatter packed (dstLocal<<24 | src) into coarse buckets (4 B/edge; src < 2^24)
__global__ void coarse_scatter_kernel(const int* __restrict__ src, const int* __restrict__ dst,
                                      const int* __restrict__ cntCB, const int* __restrict__ cb,
                                      uint* __restrict__ coarse, int ne, int epb) {
    __shared__ int cur[CB];
    int t = threadIdx.x;
    for (int i = t; i < CB; i += blockDim.x)
        cur[i] = cb[i] + cntCB[i * NBLK + blockIdx.x];
    __syncthreads();
    int e0 = blockIdx.x * epb;
    int e1 = min(e0 + epb, ne);
    for (int e = e0 + t; e < e1; e += blockDim.x) {
        int d = dst[e];
        int pos = atomicAdd(&cur[d >> 8], 1);       // LDS atomic
        coarse[pos] = ((uint)(d & 255) << 24) | (uint)src[e];
    }
}

// one block per coarse bucket: local counting sort over 256 node bins;
// emits rowptr, dinv, csr (src only)
__global__ void bucket_kernel(const uint* __restrict__ coarse, const int* __restrict__ cb,
                              int* __restrict__ rowptr, float* __restrict__ dinv,
                              int* __restrict__ csr, int n) {
    __shared__ int hist[256];
    __shared__ int excl[256];
    __shared__ int cursor[256];
    int k = blockIdx.x;
    int t = threadIdx.x;              // 256 threads
    int base = cb[k];
    int end = cb[k + 1];
    hist[t] = 0;
    __syncthreads();
    for (int i = base + t; i < end; i += 256)
        atomicAdd(&hist[coarse[i] >> 24], 1);
    __syncthreads();
    int v = hist[t];
    excl[t] = v;
    __syncthreads();
    for (int off = 1; off < 256; off <<= 1) {
        int add = (t >= off) ? excl[t - off] : 0;
        __syncthreads();
        excl[t] += add;
        __syncthreads();
    }
    int ex = excl[t] - v;                           // exclusive prefix
    int node = (k << 8) + t;
    if (node < n) {
        rowptr[node] = base + ex;
        dinv[node] = rsqrtf(1.0f + (float)v);
    }
    cursor[t] = base + ex;
    __syncthreads();
    for (int i = base + t; i < end; i += 256) {
        uint e = coarse[i];
        int pos = atomicAdd(&cursor[e >> 24], 1);   // LDS atomic
        csr[pos] = (int)(e & 0x00FFFFFFu);
    }
}

// ---------------- W -> bf16 MFMA B-fragments + zero-row init (once per call) ----------------
__global__ void wfrag_kernel(const float* __restrict__ W1, const float* __restrict__ W2,
                             uint4* __restrict__ frag, uint* __restrict__ z1,
                             uint* __restrict__ z2, int n) {
    if (blockIdx.x == 4) {                             // zero row n of hsB / hsB2
        int t = threadIdx.x;
        if (t < 32) z1[(long long)n * 32 + t] = 0u;
        else if (t < 64) z2[(long long)n * 32 + (t - 32)] = 0u;
        return;
    }
    int tid = blockIdx.x * blockDim.x + threadIdx.x;   // 0..1023
    int mat = tid >> 9;
    int rem = tid & 511;
    int nt = rem >> 7;
    int kb = (rem >> 6) & 1;
    int lane = rem & 63;
    const float* W = mat ? W2 : W1;
    int kbase = kb * 32 + (lane >> 4) * 8;
    int col = nt * 16 + (lane & 15);
    uint r[4];
#pragma unroll
    for (int j = 0; j < 4; ++j) {
        float lo = W[(kbase + 2 * j) * NCH + col];
        float hi = W[(kbase + 2 * j + 1) * NCH + col];
        r[j] = pack2bf(lo, hi);                       // slot 2j low, 2j+1 high (ascending k)
    }
    frag[tid] = make_uint4(r[0], r[1], r[2], r[3]);
}

// ---------------- H(bf16) = dinv[row] * X @ W via MFMA ----------------
// BF16A=false: X is f32 rows. BF16A=true: X is bf16 rows in (w,w+32)-packed words.
// Output word w of row = channels (w, w+32):  H[row][w] = pack(h[w], h[w+32]).
template<bool BF16A>
__global__ void gemm_mfma_kernel(const void* __restrict__ Xv, const uint4* __restrict__ wfrag,
                                 const float* __restrict__ dinv, uint* __restrict__ H, int n) {
    int lane = threadIdx.x & 63;
    int wave = blockIdx.x * (blockDim.x >> 6) + (threadIdx.x >> 6);
    int rb = wave * 16;
    if (rb >= n) return;

    short8 bfrag[4][2];
#pragma unroll
    for (int nt = 0; nt < 4; ++nt)
#pragma unroll
        for (int kb = 0; kb < 2; ++kb) {
            uint4 u = wfrag[(nt * 2 + kb) * 64 + lane];
            bfrag[nt][kb] = *(short8*)&u;
        }

    short8 afrag[2];
    if (BF16A) {
        const uint* hr = (const uint*)Xv + (long long)(rb + (lane & 15)) * 32 + (lane >> 4) * 8;
        uint4 a0 = *(const uint4*)(hr);
        uint4 a1 = *(const uint4*)(hr + 4);
        uint w[8] = {a0.x, a0.y, a0.z, a0.w, a1.x, a1.y, a1.z, a1.w};
        short8 f0, f1;
#pragma unroll
        for (int j = 0; j < 8; ++j) {
            f0[j] = (short)(w[j] & 0xffffu);
            f1[j] = (short)(w[j] >> 16);
        }
        afrag[0] = f0;
        afrag[1] = f1;
    } else {
        const float* xr = (const float*)Xv + (long long)(rb + (lane & 15)) * NCH + (lane >> 4) * 8;
#pragma unroll
        for (int kb = 0; kb < 2; ++kb) {
            float4 v0 = *(const float4*)(xr + kb * 32);
            float4 v1 = *(const float4*)(xr + kb * 32 + 4);
            short8 a;
            a[0] = (short)bf16rne(v0.x); a[1] = (short)bf16rne(v0.y);
            a[2] = (short)bf16rne(v0.z); a[3] = (short)bf16rne(v0.w);
            a[4] = (short)bf16rne(v1.x); a[5] = (short)bf16rne(v1.y);
            a[6] = (short)bf16rne(v1.z); a[7] = (short)bf16rne(v1.w);
            afrag[kb] = a;
        }
    }

    floatx4 acc[4];
#pragma unroll
    for (int nt = 0; nt < 4; ++nt) acc[nt] = (floatx4){0.f, 0.f, 0.f, 0.f};
#pragma unroll
    for (int nt = 0; nt < 4; ++nt)
#pragma unroll
        for (int kb = 0; kb < 2; ++kb)
            acc[nt] = __builtin_amdgcn_mfma_f32_16x16x32_bf16(afrag[kb], bfrag[nt][kb], acc[nt], 0, 0, 0);

    int r0 = rb + (lane >> 4) * 4;
#pragma unroll
    for (int reg = 0; reg < 4; ++reg) {
        float di = dinv[r0 + reg];
        long long roww = (long long)(r0 + reg) * 32;
#pragma unroll
        for (int nt = 0; nt < 2; ++nt) {
            int w = nt * 16 + (lane & 15);
            H[roww + w] = pack2bf(di * acc[nt][reg], di * acc[nt + 2][reg]);
        }
    }
}

// ---------------- agg: out[d,:] = act( dinv[d] * (hs[d,:] + sum_{s in N(d)} hs[s,:]) + b ) ----
// one wave per node; lane = (oct o, quad u): uint4 gathers cover 8 rows/instr.
// Single fully-predicated 32-edge round, 4 gathers in flight; masked slots
// gather the all-zero row n (adds 0.0 -> no per-element masking, no tail code).
template<bool BF16OUT>
__global__ void agg_kernel(const uint* __restrict__ hsB, const int* __restrict__ rowptr,
                           const int* __restrict__ csr, const float* __restrict__ dinv,
                           const float* __restrict__ b, void* __restrict__ outv, int n) {
    int wid = (blockIdx.x * blockDim.x + threadIdx.x) >> 6;
    if (wid >= n) return;
    wid = __builtin_amdgcn_readfirstlane(wid);        // wave-uniform -> SGPR loads
    int lane = threadIdx.x & 63;
    int o = lane >> 3;                                // oct: edge slot within round
    int u = lane & 7;                                 // quad: words 4u..4u+3
    int start = rowptr[wid];
    int end = rowptr[wid + 1];
    const uint4* __restrict__ base = (const uint4*)hsB + u;   // row = 8 uint4
    // self-loop: oct 0 reads own row, others read zero row
    int ss = (o == 0) ? wid : n;
    uint4 v = base[(long long)ss * 8];
    float a0l = unpLo(v.x), a0h = unpHi(v.x);
    float a1l = unpLo(v.y), a1h = unpHi(v.y);
    float a2l = unpLo(v.z), a2h = unpHi(v.z);
    float a3l = unpLo(v.w), a3h = unpHi(v.w);
    for (int eb = start; eb < end; eb += 32) {
        int s0 = csr[eb + o];                         // csr padded 128B: loads safe
        int s1 = csr[eb + 8 + o];
        int s2 = csr[eb + 16 + o];
        int s3 = csr[eb + 24 + o];
        s0 = (eb + o      < end) ? s0 : n;            // masked -> zero row
        s1 = (eb + 8 + o  < end) ? s1 : n;
        s2 = (eb + 16 + o < end) ? s2 : n;
        s3 = (eb + 24 + o < end) ? s3 : n;
        uint4 g0 = base[(long long)s0 * 8];
        uint4 g1 = base[(long long)s1 * 8];
        uint4 g2 = base[(long long)s2 * 8];
        uint4 g3 = base[(long long)s3 * 8];
        a0l += (unpLo(g0.x) + unpLo(g1.x)) + (unpLo(g2.x) + unpLo(g3.x));
        a0h += (unpHi(g0.x) + unpHi(g1.x)) + (unpHi(g2.x) + unpHi(g3.x));
        a1l += (unpLo(g0.y) + unpLo(g1.y)) + (unpLo(g2.y) + unpLo(g3.y));
        a1h += (unpHi(g0.y) + unpHi(g1.y)) + (unpHi(g2.y) + unpHi(g3.y));
        a2l += (unpLo(g0.z) + unpLo(g1.z)) + (unpLo(g2.z) + unpLo(g3.z));
        a2h += (unpHi(g0.z) + unpHi(g1.z)) + (unpHi(g2.z) + unpHi(g3.z));
        a3l += (unpLo(g0.w) + unpLo(g1.w)) + (unpLo(g2.w) + unpLo(g3.w));
        a3h += (unpHi(g0.w) + unpHi(g1.w)) + (unpHi(g2.w) + unpHi(g3.w));
    }
    // reduce across octs (same u): xor 8, 16, 32
#pragma unroll
    for (int m = 8; m <= 32; m <<= 1) {
        a0l += __shfl_xor(a0l, m, 64); a0h += __shfl_xor(a0h, m, 64);
        a1l += __shfl_xor(a1l, m, 64); a1h += __shfl_xor(a1h, m, 64);
        a2l += __shfl_xor(a2l, m, 64); a2h += __shfl_xor(a2h, m, 64);
        a3l += __shfl_xor(a3l, m, 64); a3h += __shfl_xor(a3h, m, 64);
    }
    if (o == 0) {                                     // 8 lanes store the row
        float d = dinv[wid];
        float4 bl = *(const float4*)(b + 4 * u);       // ch 4u..4u+3
        float4 bh = *(const float4*)(b + 4 * u + 32);  // ch 4u+32..
        float r0l = d * a0l + bl.x, r1l = d * a1l + bl.y;
        float r2l = d * a2l + bl.z, r3l = d * a3l + bl.w;
        float r0h = d * a0h + bh.x, r1h = d * a1h + bh.y;
        float r2h = d * a2h + bh.z, r3h = d * a3h + bh.w;
        if (BF16OUT) {
            uint4 w;
            w.x = pack2bf(fmaxf(r0l, 0.f), fmaxf(r0h, 0.f));
            w.y = pack2bf(fmaxf(r1l, 0.f), fmaxf(r1h, 0.f));
            w.z = pack2bf(fmaxf(r2l, 0.f), fmaxf(r2h, 0.f));
            w.w = pack2bf(fmaxf(r3l, 0.f), fmaxf(r3h, 0.f));
            *((uint4*)outv + (long long)wid * 8 + u) = w;
        } else {
            float* out = (float*)outv + (long long)wid * NCH;
            *(float4*)(out + 4 * u) = make_float4(r0l, r1l, r2l, r3l);
            *(float4*)(out + 4 * u + 32) = make_float4(r0h, r1h, r2h, r3h);
        }
    }
}

extern "C" void kernel_launch(void* const* d_in, const int* in_sizes, int n_in,
                              void* d_out, int out_size, void* d_ws, size_t ws_size,
                              hipStream_t stream) {
    const float* x  = (const float*)d_in[0];
    const int*   ei = (const int*)d_in[1];
    const float* W1 = (const float*)d_in[2];
    const float* b1 = (const float*)d_in[3];
    const float* W2 = (const float*)d_in[4];
    const float* b2 = (const float*)d_in[5];
    const int n  = in_sizes[0] / NCH;   // 100000
    const int ne = in_sizes[1] / 2;     // 1600000
    const int* src = ei;
    const int* dst = ei + ne;

    // workspace layout (all 256B-aligned)
    char* ws = (char*)d_ws;
    size_t off = 0;
    auto alloc = [&](size_t bytes) { void* p = ws + off; off += (bytes + 255) & ~(size_t)255; return p; };
    int*   cntCB   = (int*)alloc((size_t)CB * NBLK * 4);       // 1 MB
    int*   binTot  = (int*)alloc((size_t)CB * 4);
    int*   cb      = (int*)alloc((size_t)(CB + 1) * 4);
    int*   rowptr  = (int*)alloc((size_t)(n + 1) * 4);
    float* dinv    = (float*)alloc((size_t)n * 4);
    int*   csr     = (int*)alloc((size_t)ne * 4 + 128);        // +128B pad for round loads
    uint*  coarse  = (uint*)alloc((size_t)ne * 4);             // 6.4 MB packed
    uint*  hsB     = (uint*)alloc((size_t)(n + 1) * 32 * 4);   // 12.8 MB + zero row
    uint*  hsB2    = (uint*)alloc((size_t)(n + 1) * 32 * 4);   // 12.8 MB + zero row
    uint4* wfrag   = (uint4*)alloc(1024 * 16);                 // 16 KB

    const int blk = 256;
    const int gAgg = (n * 64 + blk - 1) / blk;                 // wave per node
    const int epb  = (ne + NBLK - 1) / NBLK;
    const int nBuck = (n + 255) / 256;
    const int nWaveG = (n + 15) / 16;
    const int gGemm = (nWaveG + 3) / 4;

    // ---- CSR build (no global atomics) + W fragment pack + zero rows ----
    wfrag_kernel         <<<5, 256, 0, stream>>>(W1, W2, wfrag, hsB, hsB2, n);
    coarse_hist_kernel   <<<NBLK, blk, 0, stream>>>(dst, cntCB, ne, epb);
    binscan_kernel       <<<CB, NBLK, 0, stream>>>(cntCB, binTot);
    cbscan_kernel        <<<1, CB, 0, stream>>>(binTot, cb, rowptr, n, ne);
    coarse_scatter_kernel<<<NBLK, blk, 0, stream>>>(src, dst, cntCB, cb, coarse, ne, epb);
    bucket_kernel        <<<nBuck, 256, 0, stream>>>(coarse, cb, rowptr, dinv, csr, n);

    // ---- layer 1 ----
    gemm_mfma_kernel<false><<<gGemm, blk, 0, stream>>>(x, wfrag, dinv, hsB, n);
    agg_kernel<true><<<gAgg, blk, 0, stream>>>(hsB, rowptr, csr, dinv, b1, hsB2, n);

    // ---- layer 2 (relu pre-applied by agg1; A read as packed bf16) ----
    gemm_mfma_kernel<true><<<gGemm, blk, 0, stream>>>(hsB2, wfrag + 512, dinv, hsB, n);
    agg_kernel<false><<<gAgg, blk, 0, stream>>>(hsB, rowptr, csr, dinv, b2, d_out, n);
}